// Round 1
// baseline (59643.329 us; speedup 1.0000x reference)
//
#include <hip/hip_runtime.h>
#include <hip/hip_cooperative_groups.h>
#include <math.h>

namespace cg = cooperative_groups;

static constexpr int Bz = 128;
static constexpr int Tt = 1024;
static constexpr int Hh = 512;
static constexpr int Cc = 10;

static constexpr int JB = 32;            // hidden-dim partitions (blocks)
static constexpr int NBp = 8;            // batch partitions (blocks)
static constexpr int JU = Hh / JB;       // 16 units per block
static constexpr int NBATCH = Bz / NBp;  // 16 batch rows per block
static constexpr int THREADS = 512;
static constexpr int GRID = JB * NBp;    // 256 blocks

// workspace layout (floats)
static constexpr int WS_H = 0;                          // h[2][B][H] = 131072 floats
static constexpr int WS_PART = 2 * Bz * Hh;             // part[2][JB][B][12] = 98304 floats
static constexpr int PART_STRIDE_STEP = JB * Bz * 12;

__global__ __launch_bounds__(THREADS, 2)
void lstm_fused(const float* __restrict__ x,
                const float* __restrict__ w_ih,
                const float* __restrict__ w_hh,
                const float* __restrict__ b_ih,
                const float* __restrict__ b_hh,
                const float* __restrict__ w_t,
                const float* __restrict__ w_fc,
                const float* __restrict__ b_fc,
                float* __restrict__ out,
                float* __restrict__ ws)
{
    cg::grid_group grid = cg::this_grid();
    const int bid = blockIdx.x;
    const int jb = bid % JB;     // hidden-slice id
    const int nb = bid / JB;     // batch-slice id
    const int t = threadIdx.x;

    float* hbuf = ws + WS_H;
    float* part = ws + WS_PART;

    // zero h[step=0] buffer (ws is poisoned by the harness)
    for (int i = bid * THREADS + t; i < Bz * Hh; i += GRID * THREADS)
        hbuf[i] = 0.0f;

    // ---- elementwise role (threads 0..255): one (unit, batch) tuple each ----
    const int u = t % JU;            // unit within slice
    const int bb = t / JU;           // local batch (valid when t < 256)
    const int gj = jb * JU + u;      // global hidden unit
    const int gb = nb * NBATCH + bb; // global batch
    float wih_r[4], bias_r[4], wfc_r[Cc];
    float w1r = 0.f, w2r = 0.f;
    if (t < JU * NBATCH) {
        #pragma unroll
        for (int g = 0; g < 4; ++g) {
            wih_r[g]  = w_ih[g * Hh + gj];
            bias_r[g] = b_ih[g * Hh + gj] + b_hh[g * Hh + gj];
        }
        w1r = w_t[gj];
        w2r = w_t[Hh + gj];
        #pragma unroll
        for (int c = 0; c < Cc; ++c) wfc_r[c] = w_fc[c * Hh + gj];
    }
    float creg = 0.0f;  // persistent cell state for (gj, gb)

    // ---- consumer role: jb==0 blocks, threads 0..159 own (batch, channel) ----
    const bool is_cons = (jb == 0) && (t < NBATCH * Cc);
    const int cb = t / Cc, cc = t % Cc;
    const int cgb = nb * NBATCH + cb;
    float S1w = 0.f, S2w = 0.f;
    const float bfc = is_cons ? b_fc[cc] : 0.f;

    // ---- GEMM role: 64 local rows x 16 batch, 2 accumulators/thread ----
    const int lr = t % 64;                 // local row = g*JU + u2
    const int bg = t / 64;                 // batch pair group 0..7
    const int grow = (lr / JU) * Hh + jb * JU + (lr % JU);  // global w_hh row
    const float* wrow = w_hh + (size_t)grow * Hh;
    const int b0 = bg * 2, b1 = b0 + 1;

    __shared__ __align__(16) float hs[NBATCH][Hh];     // 32 KB staged h slice
    __shared__ float gbuf[64][NBATCH + 1];             // +1 pad: kill bank conflicts

    grid.sync();  // h[0] zeroed everywhere

    for (int step = 0; step < Tt; ++step) {
        const int rb = step & 1, wb = rb ^ 1;

        // stage this block's h slice (16 x 512) into LDS, float4-coalesced
        {
            const float4* s4 = (const float4*)(hbuf + (size_t)rb * Bz * Hh
                                               + (size_t)(nb * NBATCH) * Hh);
            float4* d4 = (float4*)hs;
            #pragma unroll
            for (int i = t; i < NBATCH * Hh / 4; i += THREADS) d4[i] = s4[i];
        }
        __syncthreads();

        // 64x16 gate tile: gates[r][b] = sum_k w_hh[grow][k] * h[b][k]
        float acc0 = 0.f, acc1 = 0.f;
        #pragma unroll 4
        for (int k = 0; k < Hh; k += 4) {
            const float4 wv = *(const float4*)(wrow + k);
            const float4 h0 = *(const float4*)(&hs[b0][k]);
            const float4 h1 = *(const float4*)(&hs[b1][k]);
            acc0 += wv.x * h0.x + wv.y * h0.y + wv.z * h0.z + wv.w * h0.w;
            acc1 += wv.x * h1.x + wv.y * h1.y + wv.z * h1.z + wv.w * h1.w;
        }
        gbuf[lr][b0] = acc0;
        gbuf[lr][b1] = acc1;
        __syncthreads();

        // LSTM elementwise + projected reductions
        if (t < JU * NBATCH) {
            const float xv = x[(size_t)gb * Tt + step];
            const float gi = gbuf[0 * JU + u][bb] + xv * wih_r[0] + bias_r[0];
            const float gf = gbuf[1 * JU + u][bb] + xv * wih_r[1] + bias_r[1];
            const float gg = gbuf[2 * JU + u][bb] + xv * wih_r[2] + bias_r[2];
            const float go = gbuf[3 * JU + u][bb] + xv * wih_r[3] + bias_r[3];
            const float si = 1.f / (1.f + expf(-gi));
            const float sf = 1.f / (1.f + expf(-gf));
            const float so = 1.f / (1.f + expf(-go));
            creg = sf * creg + si * tanhf(gg);
            const float hnew = so * tanhf(creg);

            hbuf[(size_t)wb * Bz * Hh + (size_t)gb * Hh + gj] = hnew;

            // partial projections over this block's 16 units
            float p1 = hnew * w1r;    // -> a_t
            float p2 = hnew * w2r;    // -> b2_t
            float pc[Cc];
            #pragma unroll
            for (int c = 0; c < Cc; ++c) pc[c] = hnew * wfc_r[c];  // -> hw_t

            #pragma unroll
            for (int m = JU / 2; m >= 1; m >>= 1) {
                p1 += __shfl_xor(p1, m, JU);
                p2 += __shfl_xor(p2, m, JU);
                #pragma unroll
                for (int c = 0; c < Cc; ++c) pc[c] += __shfl_xor(pc[c], m, JU);
            }
            if (u == 0) {
                float* pp = part + (size_t)rb * PART_STRIDE_STEP
                                 + ((size_t)jb * Bz + gb) * 12;
                pp[0] = p1;
                pp[1] = p2;
                #pragma unroll
                for (int c = 0; c < Cc; ++c) pp[2 + c] = pc[c];
            }
        }

        grid.sync();  // h_t and partials visible device-wide

        // consumer: fold partials, emit 10 output channels per batch row
        if (is_cons) {
            const float* pb = part + (size_t)rb * PART_STRIDE_STEP + (size_t)cgb * 12;
            float a = 0.f, b2 = 0.f, hw = 0.f;
            #pragma unroll 8
            for (int j = 0; j < JB; ++j) {
                const float* q = pb + (size_t)j * Bz * 12;
                a  += q[0];
                b2 += q[1];
                hw += q[2 + cc];
            }
            out[((size_t)cgb * Tt + step) * Cc + cc] = hw + a * S1w + S2w + bfc;
            S1w += hw;          // S1 @ w_fc.T accumulates h @ w_fc.T
            S2w += b2 * hw;     // S2 @ w_fc.T accumulates (h.w2) * (h @ w_fc.T)
        }
        // next step writes the other h/part buffers -> one sync per step suffices
    }
}

extern "C" void kernel_launch(void* const* d_in, const int* in_sizes, int n_in,
                              void* d_out, int out_size, void* d_ws, size_t ws_size,
                              hipStream_t stream)
{
    const float* xp  = (const float*)d_in[0];
    const float* wih = (const float*)d_in[1];
    const float* whh = (const float*)d_in[2];
    const float* bih = (const float*)d_in[3];
    const float* bhh = (const float*)d_in[4];
    const float* wt  = (const float*)d_in[5];
    const float* wfc = (const float*)d_in[6];
    const float* bfc = (const float*)d_in[7];
    float* outp = (float*)d_out;
    float* ws   = (float*)d_ws;

    void* args[] = { &xp, &wih, &whh, &bih, &bhh, &wt, &wfc, &bfc, &outp, &ws };
    hipLaunchCooperativeKernel((const void*)lstm_fused, dim3(GRID), dim3(THREADS),
                               args, 0, stream);
}

// Round 3
// 48356.421 us; speedup vs baseline: 1.2334x; 1.2334x over previous
//
#include <hip/hip_runtime.h>
#include <math.h>

static constexpr int Bz = 128;
static constexpr int Tt = 1024;
static constexpr int Hh = 512;
static constexpr int Cc = 10;

static constexpr int JB  = 64;            // hidden-slice blocks per group
static constexpr int NBp = 4;             // batch groups
static constexpr int UPB = 8;             // units per block (-> 32 gate rows)
static constexpr int BPB = 32;            // batch rows per group
static constexpr int THREADS = 256;
static constexpr int GRID = JB * NBp;     // 256 blocks = 256 CUs, 1 per CU

// ws layout: int flags[256] (1 KB) | h[2][Bz][Hh] fp32 (524 KB). Total 525 KB.
static constexpr size_t WS_H = 256;       // float offset of h

__device__ __forceinline__ float dot4(float4 a, float4 b) {
    return a.x * b.x + a.y * b.y + a.z * b.z + a.w * b.w;
}

__global__ __launch_bounds__(THREADS, 1)
void lstm_fused(const float* __restrict__ x,
                const float* __restrict__ w_ih,
                const float* __restrict__ w_hh,
                const float* __restrict__ b_ih,
                const float* __restrict__ b_hh,
                const float* __restrict__ w_t,
                const float* __restrict__ w_fc,
                const float* __restrict__ b_fc,
                float* __restrict__ out,
                float* __restrict__ ws)
{
    const int tid  = threadIdx.x;
    const int bid  = blockIdx.x;
    // XCD-paired mapping: group nb lives on XCDs {2nb, 2nb+1}
    const int nb   = (bid >> 1) & 3;
    const int jb   = ((bid >> 3) << 1) | (bid & 1);
    const int lane = tid & 63;
    const int wv   = tid >> 6;             // wave id 0..3 = gate id in GEMM
    const int ks   = lane & 15;            // K-slice lane
    const int bg   = lane >> 4;            // batch group of 8

    int*   flags = (int*)ws;
    float* hglob = ws + WS_H;

    // LDS: persistent weight slice (64K) + h tile (64K) + gate buffer (4.6K)
    __shared__ float4 wls[32 * 128];
    __shared__ float4 hls[32 * 128];
    __shared__ float  gbuf[32 * 36];

    // ---- preload this block's w_hh slice (8 units x 4 gates x 512) ----
    #pragma unroll
    for (int g = 0; g < 4; ++g) {
        const float4* src = (const float4*)w_hh + (size_t)(g * Hh + jb * UPB) * (Hh / 4);
        #pragma unroll
        for (int n = 0; n < 4; ++n)
            wls[g * 1024 + n * 256 + tid] = src[n * 256 + tid];
    }

    // ---- elementwise role: thread -> (u, b) ----
    const int u  = tid & 7;
    const int b_ = tid >> 3;               // 0..31
    const int gj = jb * UPB + u;
    const int gb = nb * BPB + b_;
    float wih_r[4], bias_r[4];
    #pragma unroll
    for (int g = 0; g < 4; ++g) {
        wih_r[g]  = w_ih[g * Hh + gj];
        bias_r[g] = b_ih[g * Hh + gj] + b_hh[g * Hh + gj];
    }
    float creg = 0.0f;

    // ---- owner role: even-jb blocks own one batch row's output recurrence ----
    const bool owner_blk = ((jb & 1) == 0);
    const int  gb_own    = nb * BPB + (jb >> 1);
    float S1w[Cc], S2w[Cc], bfc_r[Cc];
    #pragma unroll
    for (int c = 0; c < Cc; ++c) { S1w[c] = 0.f; S2w[c] = 0.f; bfc_r[c] = b_fc[c]; }

    for (int t = 0; t < Tt; ++t) {
        const int rb = t & 1, wb = rb ^ 1;

        // ---- A: stage h_t (32 batch x 512) into LDS ----
        if (t == 0) {
            const float4 z = make_float4(0.f, 0.f, 0.f, 0.f);
            #pragma unroll
            for (int n = 0; n < 16; ++n) hls[n * 256 + tid] = z;
        } else {
            const float4* src = (const float4*)hglob + (size_t)(rb * Bz + nb * BPB) * 128;
            #pragma unroll
            for (int n = 0; n < 16; ++n) hls[n * 256 + tid] = src[n * 256 + tid];
        }
        __syncthreads();

        // ---- B: GEMM 32x32x512, wave = gate, 8x8 reg tile, K split 16 ways ----
        float acc[8][8];
        #pragma unroll
        for (int j = 0; j < 8; ++j)
            #pragma unroll
            for (int i = 0; i < 8; ++i) acc[j][i] = 0.f;

        #pragma unroll
        for (int q = 0; q < 8; ++q) {
            const int kq = ks + q * 16;
            float4 wf[8], hv[8];
            #pragma unroll
            for (int j = 0; j < 8; ++j) wf[j] = wls[(wv * 8 + j) * 128 + kq];
            #pragma unroll
            for (int i = 0; i < 8; ++i) hv[i] = hls[(bg * 8 + i) * 128 + kq];
            #pragma unroll
            for (int j = 0; j < 8; ++j)
                #pragma unroll
                for (int i = 0; i < 8; ++i)
                    acc[j][i] += wf[j].x * hv[i].x + wf[j].y * hv[i].y
                               + wf[j].z * hv[i].z + wf[j].w * hv[i].w;
        }
        #pragma unroll
        for (int m = 1; m <= 8; m <<= 1)
            #pragma unroll
            for (int j = 0; j < 8; ++j)
                #pragma unroll
                for (int i = 0; i < 8; ++i)
                    acc[j][i] += __shfl_xor(acc[j][i], m, 64);

        if (ks == 0) {
            #pragma unroll
            for (int j = 0; j < 8; ++j) {
                float* gr = &gbuf[(wv * 8 + j) * 36 + bg * 8];
                *(float4*)(gr + 0) = make_float4(acc[j][0], acc[j][1], acc[j][2], acc[j][3]);
                *(float4*)(gr + 4) = make_float4(acc[j][4], acc[j][5], acc[j][6], acc[j][7]);
            }
        }
        __syncthreads();

        // ---- C: LSTM elementwise, write h_t ----
        {
            const float xv = x[(size_t)gb * Tt + t];
            const float gi = gbuf[(0 * 8 + u) * 36 + b_] + xv * wih_r[0] + bias_r[0];
            const float gf = gbuf[(1 * 8 + u) * 36 + b_] + xv * wih_r[1] + bias_r[1];
            const float gg = gbuf[(2 * 8 + u) * 36 + b_] + xv * wih_r[2] + bias_r[2];
            const float go = gbuf[(3 * 8 + u) * 36 + b_] + xv * wih_r[3] + bias_r[3];
            const float si = 1.f / (1.f + expf(-gi));
            const float sf = 1.f / (1.f + expf(-gf));
            const float so = 1.f / (1.f + expf(-go));
            creg = sf * creg + si * tanhf(gg);
            const float hnew = so * tanhf(creg);
            hglob[((size_t)wb * Bz + gb) * Hh + gj] = hnew;
        }
        __syncthreads();   // drains all stores to L2 (vmcnt(0) before s_barrier)

        // ---- D: arrive (release: L2 writeback before flag becomes visible) ----
        if (tid == 0) {
            __threadfence();
            __hip_atomic_store(&flags[nb * JB + jb], t + 1,
                               __ATOMIC_RELEASE, __HIP_MEMORY_SCOPE_AGENT);
        }

        // ---- E: wave 0 waits for the 64 group peers; owner emits output ----
        if (wv == 0) {
            int v = __hip_atomic_load(&flags[nb * JB + lane],
                                      __ATOMIC_RELAXED, __HIP_MEMORY_SCOPE_AGENT);
            while (__any(v < t + 1)) {
                __builtin_amdgcn_s_sleep(1);
                v = __hip_atomic_load(&flags[nb * JB + lane],
                                      __ATOMIC_RELAXED, __HIP_MEMORY_SCOPE_AGENT);
            }
            __threadfence();  // acquire: invalidate stale L1/L2 before reading h

            if (owner_blk) {
                // recompute the 12 projections of h_t[gb_own] directly
                const float4* hr  = (const float4*)hglob
                                    + ((size_t)wb * Bz + gb_own) * 128 + lane * 2;
                const float4  hA  = hr[0], hB = hr[1];
                const float4* wt4 = (const float4*)w_t;
                const float4* wf4 = (const float4*)w_fc;
                float r[12];
                r[0] = dot4(hA, wt4[lane * 2])       + dot4(hB, wt4[lane * 2 + 1]);
                r[1] = dot4(hA, wt4[128 + lane * 2]) + dot4(hB, wt4[128 + lane * 2 + 1]);
                #pragma unroll
                for (int c = 0; c < Cc; ++c)
                    r[2 + c] = dot4(hA, wf4[c * 128 + lane * 2])
                             + dot4(hB, wf4[c * 128 + lane * 2 + 1]);
                #pragma unroll
                for (int m = 1; m <= 32; m <<= 1)
                    #pragma unroll
                    for (int k2 = 0; k2 < 12; ++k2)
                        r[k2] += __shfl_xor(r[k2], m, 64);

                if (lane == 0) {
                    const float a = r[0], b2 = r[1];
                    float* po = out + ((size_t)gb_own * Tt + t) * Cc;
                    #pragma unroll
                    for (int c = 0; c < Cc; ++c) {
                        const float hw = r[2 + c];
                        po[c] = hw + a * S1w[c] + S2w[c] + bfc_r[c];
                        S1w[c] += hw;
                        S2w[c] += b2 * hw;
                    }
                }
            }
        }
        __syncthreads();   // block proceeds only after barrier + owner phase
    }
}

extern "C" void kernel_launch(void* const* d_in, const int* in_sizes, int n_in,
                              void* d_out, int out_size, void* d_ws, size_t ws_size,
                              hipStream_t stream)
{
    const float* xp  = (const float*)d_in[0];
    const float* wih = (const float*)d_in[1];
    const float* whh = (const float*)d_in[2];
    const float* bih = (const float*)d_in[3];
    const float* bhh = (const float*)d_in[4];
    const float* wt  = (const float*)d_in[5];
    const float* wfc = (const float*)d_in[6];
    const float* bfc = (const float*)d_in[7];
    float* outp = (float*)d_out;
    float* ws   = (float*)d_ws;

    // zero the flag array (first 1 KB of ws) each call; graph-capturable
    hipMemsetAsync(d_ws, 0, 1024, stream);

    hipLaunchKernelGGL(lstm_fused, dim3(GRID), dim3(THREADS), 0, stream,
                       xp, wih, whh, bih, bhh, wt, wfc, bfc, outp, ws);
}

// Round 5
// 47452.594 us; speedup vs baseline: 1.2569x; 1.0190x over previous
//
#include <hip/hip_runtime.h>
#include <math.h>

static constexpr int Bz = 128;
static constexpr int Tt = 1024;
static constexpr int Hh = 512;
static constexpr int Cc = 10;

static constexpr int NXCD = 8;       // XCDs; each runs an independent group
static constexpr int BPX  = 32;      // blocks (CUs) per XCD
static constexpr int UPB  = 16;      // hidden units per block (64 gate rows)
static constexpr int NB   = 16;      // batch rows per XCD (8*16 = 128)
static constexpr int THREADS = 256;
static constexpr int GRID = 256;     // 1 block per CU (LDS-forced)

// ws: [0,1024) flags[8][32] int | [1024,1056) counters[8] int | pad
//     float offset 1024: h[2][8][16][512]  (528 KB total)
static constexpr size_t WS_H_F  = 1024;   // float offset of h
static constexpr size_t WS_H_F4 = 256;    // float4 offset of h

__device__ __forceinline__ float dot4(float4 a, float4 b) {
    return a.x * b.x + a.y * b.y + a.z * b.z + a.w * b.w;
}

__global__ __launch_bounds__(THREADS, 1)
void lstm_fused(const float* __restrict__ x,
                const float* __restrict__ w_ih,
                const float* __restrict__ w_hh,
                const float* __restrict__ b_ih,
                const float* __restrict__ b_hh,
                const float* __restrict__ w_t,
                const float* __restrict__ w_fc,
                const float* __restrict__ b_fc,
                float* __restrict__ out,
                float* __restrict__ ws)
{
    const int tid  = threadIdx.x;
    const int lane = tid & 63;
    const int wv   = tid >> 6;        // wave id = gate id in GEMM
    const int ks   = lane & 15;       // K-slice lane
    const int bg   = lane >> 4;       // batch group (4 rows each)

    int*    flags    = (int*)ws;
    int*    counters = (int*)ws + 256;
    float*  hglob    = ws + WS_H_F;
    float4* h4       = (float4*)ws + WS_H_F4;

    // LDS: w slice 128 KB + h tile 32 KB = exactly 160 KiB (gbuf aliases hls)
    __shared__ float4 wls[64 * 128];
    __shared__ float4 hls[16 * 128];
    float* gbuf = (float*)hls;        // 64 x 17 floats, used only post-GEMM

    // ---- discover physical XCD, claim a rank (exchange aliased into hls) ----
    int* xchg = (int*)hls;            // hls is dead until loop phase A
    if (tid == 0) {
        int xr;
        asm volatile("s_getreg_b32 %0, hwreg(20, 0, 32)" : "=s"(xr));
        const int xcd = xr & 7;
        xchg[0] = xcd;
        xchg[1] = atomicAdd(&counters[xcd], 1) & 31;   // device-scope RMW
    }
    __syncthreads();
    const int xcd  = xchg[0];
    const int rank = xchg[1];
    __syncthreads();                  // everyone read before hls is reused
    const int fbase = xcd * BPX;

    // ---- preload w_hh slice: rows g*512 + rank*16 + j  ->  wls[g*16+j] ----
    {
        const float4* w4 = (const float4*)w_hh;
        #pragma unroll
        for (int g = 0; g < 4; ++g)
            #pragma unroll
            for (int n = 0; n < 8; ++n) {
                const int idx = n * 256 + tid;        // 0..2047
                const int j = idx >> 7, col = idx & 127;
                wls[(g * UPB + j) * 128 + col] =
                    w4[(size_t)(g * Hh + rank * UPB + j) * 128 + col];
            }
    }

    // ---- elementwise role: thread -> (u, b) ----
    const int u  = tid & 15;
    const int b_ = tid >> 4;                 // 0..15
    const int gj = rank * UPB + u;           // global hidden unit
    const int gb = xcd * NB + b_;            // global batch row
    float wih_r[4], bias_r[4];
    #pragma unroll
    for (int g = 0; g < 4; ++g) {
        wih_r[g]  = w_ih[g * Hh + gj];
        bias_r[g] = b_ih[g * Hh + gj] + b_hh[g * Hh + gj];
    }
    float creg = 0.0f;

    // ---- owner role: ranks 0..15 own batch row xcd*16+rank ----
    const bool owner = (rank < NB);
    const int  gb_own = xcd * NB + rank;
    float S1w[Cc], S2w[Cc], bfc_r[Cc];
    #pragma unroll
    for (int c = 0; c < Cc; ++c) { S1w[c] = 0.f; S2w[c] = 0.f; bfc_r[c] = b_fc[c]; }

    for (int t = 0; t < Tt; ++t) {
        const int rb = t & 1, wb = rb ^ 1;

        // ---- A: stage h_t (16 x 512) into LDS (L2-local, plain loads) ----
        if (t == 0) {
            const float4 z = make_float4(0.f, 0.f, 0.f, 0.f);
            #pragma unroll
            for (int n = 0; n < 8; ++n) hls[n * 256 + tid] = z;
        } else {
            const float4* src = h4 + (size_t)(rb * NXCD + xcd) * 2048;
            #pragma unroll
            for (int n = 0; n < 8; ++n) hls[n * 256 + tid] = src[n * 256 + tid];
        }
        __syncthreads();

        // ---- B: GEMM 64x16x512, wave = gate, 16x4 reg tile, K split 16 ----
        float acc[16][4];
        #pragma unroll
        for (int j = 0; j < 16; ++j)
            #pragma unroll
            for (int i = 0; i < 4; ++i) acc[j][i] = 0.f;

        #pragma unroll
        for (int q = 0; q < 8; ++q) {
            const int kq = ks + q * 16;
            float4 hv[4];
            #pragma unroll
            for (int i = 0; i < 4; ++i) hv[i] = hls[(bg * 4 + i) * 128 + kq];
            #pragma unroll
            for (int j2 = 0; j2 < 2; ++j2) {
                float4 wf[8];
                #pragma unroll
                for (int j = 0; j < 8; ++j)
                    wf[j] = wls[(wv * UPB + j2 * 8 + j) * 128 + kq];
                #pragma unroll
                for (int j = 0; j < 8; ++j)
                    #pragma unroll
                    for (int i = 0; i < 4; ++i)
                        acc[j2 * 8 + j][i] += wf[j].x * hv[i].x + wf[j].y * hv[i].y
                                            + wf[j].z * hv[i].z + wf[j].w * hv[i].w;
            }
        }
        #pragma unroll
        for (int m = 1; m <= 8; m <<= 1)
            #pragma unroll
            for (int j = 0; j < 16; ++j)
                #pragma unroll
                for (int i = 0; i < 4; ++i)
                    acc[j][i] += __shfl_xor(acc[j][i], m, 64);

        __syncthreads();          // all hls reads done before gbuf clobbers it
        if (ks == 0) {
            #pragma unroll
            for (int j = 0; j < 16; ++j)
                #pragma unroll
                for (int i = 0; i < 4; ++i)
                    gbuf[(wv * UPB + j) * 17 + (bg * 4 + i)] = acc[j][i];
        }
        __syncthreads();

        // ---- C: LSTM elementwise, write h_t+1 (plain store -> XCD L2) ----
        {
            const float xv = x[(size_t)gb * Tt + t];
            const float gi = gbuf[(0 * UPB + u) * 17 + b_] + xv * wih_r[0] + bias_r[0];
            const float gf = gbuf[(1 * UPB + u) * 17 + b_] + xv * wih_r[1] + bias_r[1];
            const float gg = gbuf[(2 * UPB + u) * 17 + b_] + xv * wih_r[2] + bias_r[2];
            const float go = gbuf[(3 * UPB + u) * 17 + b_] + xv * wih_r[3] + bias_r[3];
            const float si = 1.f / (1.f + expf(-gi));
            const float sf = 1.f / (1.f + expf(-gf));
            const float so = 1.f / (1.f + expf(-go));
            creg = sf * creg + si * tanhf(gg);
            const float hnew = so * tanhf(creg);
            hglob[((size_t)(wb * NXCD + xcd) * NB + b_) * Hh + gj] = hnew;
        }
        __syncthreads();   // compiler emits vmcnt(0) before s_barrier: h in L2

        // ---- D: arrive (relaxed atomic flag, no cache maintenance) ----
        if (tid == 0)
            __hip_atomic_store(&flags[fbase + rank], t + 1,
                               __ATOMIC_RELAXED, __HIP_MEMORY_SCOPE_AGENT);

        // ---- E: wave 0 polls 32 XCD-local flags; L1-inv; owner emits out ----
        if (wv == 0) {
            const int fidx = fbase + (lane & 31);
            int v = __hip_atomic_load(&flags[fidx], __ATOMIC_RELAXED,
                                      __HIP_MEMORY_SCOPE_AGENT);
            while (__any(v < t + 1)) {
                __builtin_amdgcn_s_sleep(2);
                v = __hip_atomic_load(&flags[fidx], __ATOMIC_RELAXED,
                                      __HIP_MEMORY_SCOPE_AGENT);
            }
            // invalidate vector L1 only; peers' h is in our shared XCD L2
            asm volatile("buffer_inv\n\ts_waitcnt vmcnt(0)" ::: "memory");

            if (owner) {
                const float4* hr = h4 + (size_t)(wb * NXCD + xcd) * 2048
                                      + rank * 128 + lane * 2;
                const float4 hA = hr[0], hB = hr[1];
                const float4* wt4 = (const float4*)w_t;
                const float4* wf4 = (const float4*)w_fc;
                float r[12];
                r[0] = dot4(hA, wt4[lane * 2])       + dot4(hB, wt4[lane * 2 + 1]);
                r[1] = dot4(hA, wt4[128 + lane * 2]) + dot4(hB, wt4[128 + lane * 2 + 1]);
                #pragma unroll
                for (int c = 0; c < Cc; ++c)
                    r[2 + c] = dot4(hA, wf4[c * 128 + lane * 2])
                             + dot4(hB, wf4[c * 128 + lane * 2 + 1]);
                #pragma unroll
                for (int m = 1; m <= 32; m <<= 1)
                    #pragma unroll
                    for (int k2 = 0; k2 < 12; ++k2)
                        r[k2] += __shfl_xor(r[k2], m, 64);

                if (lane == 0) {
                    const float a = r[0], b2 = r[1];
                    float* po = out + ((size_t)gb_own * Tt + t) * Cc;
                    #pragma unroll
                    for (int c = 0; c < Cc; ++c) {
                        const float hw = r[2 + c];
                        po[c] = hw + a * S1w[c] + S2w[c] + bfc_r[c];
                        S1w[c] += hw;
                        S2w[c] += b2 * hw;
                    }
                }
            }
        }
        __syncthreads();   // whole block proceeds only after poll + owner phase
    }
}

extern "C" void kernel_launch(void* const* d_in, const int* in_sizes, int n_in,
                              void* d_out, int out_size, void* d_ws, size_t ws_size,
                              hipStream_t stream)
{
    const float* xp  = (const float*)d_in[0];
    const float* wih = (const float*)d_in[1];
    const float* whh = (const float*)d_in[2];
    const float* bih = (const float*)d_in[3];
    const float* bhh = (const float*)d_in[4];
    const float* wt  = (const float*)d_in[5];
    const float* wfc = (const float*)d_in[6];
    const float* bfc = (const float*)d_in[7];
    float* outp = (float*)d_out;
    float* ws   = (float*)d_ws;

    // zero flags + rank counters each call (graph-capturable)
    (void)hipMemsetAsync(d_ws, 0, 4096, stream);

    hipLaunchKernelGGL(lstm_fused, dim3(GRID), dim3(THREADS), 0, stream,
                       xp, wih, whh, bih, bhh, wt, wfc, bfc, outp, ws);
}